// Round 11
// baseline (28.237 us; speedup 1.0000x reference)
//
#include <hip/hip_runtime.h>
#include <hip/hip_fp16.h>

// Problem constants (from reference)
#define BSZ     1024   // batch
#define N_IN    1024
#define NLAYERS 5
#define NPL     2048   // nodes per layer
#define FANIN   16
#define N_OUT   256

#define VALS_ROWS   (N_IN + 4 * NPL)            // 9216 gatherable rows
#define CPB         4                           // batch columns per block
#define NBLK        (BSZ / CPB)                 // 256 blocks
#define ROW_B       8                           // 4 cols x fp16 per row
#define LDS_BYTES   (VALS_ROWS * ROW_B)         // 73728 B

union H4 { unsigned long long u; __half2 h2[2]; };

__device__ __forceinline__ float fast_tanh(float x) {
    float t = __expf(2.0f * x);
    return 1.0f - 2.0f / (t + 1.0f);
}
__device__ __forceinline__ float fast_sigmoid(float x) {
    return 1.0f / (1.0f + __expf(-x));
}

// Load one node's 16 raw edges (indices + f32 weights) into registers.
// 4x int4 + 4x float4, per-lane 64B chunks, fully unrolled (static indexing).
__device__ __forceinline__ void load_edges(
    const int* __restrict__ src, const float* __restrict__ wsrc,
    int node, int* idx, float* wv)
{
    const int4*   ip = reinterpret_cast<const int4*>(src  + (size_t)node * FANIN);
    const float4* fp = reinterpret_cast<const float4*>(wsrc + (size_t)node * FANIN);
#pragma unroll
    for (int q = 0; q < 4; ++q) {
        const int4   a = ip[q];
        const float4 b = fp[q];
        idx[4*q+0] = a.x; idx[4*q+1] = a.y; idx[4*q+2] = a.z; idx[4*q+3] = a.w;
        wv [4*q+0] = b.x; wv [4*q+1] = b.y; wv [4*q+2] = b.z; wv [4*q+3] = b.w;
    }
}

// One node: 16 x {ds_read_b64 gather, broadcast w, 2 x v_pk_fma_f16},
// f32 tanh, one ds_write_b64 of the 4xfp16 activation row.
__device__ __forceinline__ void node_tanh(
    const int* idx, const float* wv, float bvf, int row, char* lds)
{
    const __half hb = __float2half(bvf);
    __half2 a01 = __halves2half2(hb, hb);
    __half2 a23 = a01;
#pragma unroll
    for (int f = 0; f < FANIN; ++f) {
        H4 v;
        v.u = *reinterpret_cast<const unsigned long long*>(
            lds + ((unsigned)idx[f] << 3));
        const __half2 w2 = __float2half2_rn(wv[f]);
        a01 = __hfma2(v.h2[0], w2, a01);
        a23 = __hfma2(v.h2[1], w2, a23);
    }
    float a0 = fast_tanh(__half2float(__low2half(a01)));
    float a1 = fast_tanh(__half2float(__high2half(a01)));
    float a2 = fast_tanh(__half2float(__low2half(a23)));
    float a3 = fast_tanh(__half2float(__high2half(a23)));
    H4 rec;
    rec.h2[0] = __halves2half2(__float2half(a0), __float2half(a1));
    rec.h2[1] = __halves2half2(__float2half(a2), __float2half(a3));
    *reinterpret_cast<unsigned long long*>(lds + (size_t)row * ROW_B) = rec.u;
}

// ---------------------------------------------------------------------------
// Single fused whole-network kernel. Each block owns 4 batch columns; ALL
// activations live in LDS as 8-B rows [row][4 x fp16]; every gather is one
// ds_read_b64. Edge data read RAW from global (no prep kernel): idx/w double-
// buffered in registers (A/B), next sweep's loads issued before the current
// sweep's compute, next layer's before the barrier, so L2 latency hides under
// FMA + LDS work. One __syncthreads per layer (layer l writes rows above all
// rows it reads). Layer 4 computes only the 256 output-reachable nodes.
// ---------------------------------------------------------------------------
__global__ __launch_bounds__(1024) void fused_net_kernel(
    const float* __restrict__ inputs,           // (BSZ, N_IN) f32
    const int* __restrict__ src,                // (L, NPL, FANIN) i32
    const float* __restrict__ wsrc,             // (L, NPL, FANIN) f32
    const float* __restrict__ biases,           // (L, NPL) f32
    float* __restrict__ out)                    // (BSZ, N_OUT) f32
{
    extern __shared__ char lds[];
    const int tid = threadIdx.x;
    const int c0  = blockIdx.x * CPB;           // batch base for this block

    // ---- stage 4 input columns as one 8-B row record per node ----
    {
        float v0 = inputs[(size_t)(c0 + 0) * N_IN + tid];
        float v1 = inputs[(size_t)(c0 + 1) * N_IN + tid];
        float v2 = inputs[(size_t)(c0 + 2) * N_IN + tid];
        float v3 = inputs[(size_t)(c0 + 3) * N_IN + tid];
        H4 rec;
        rec.h2[0] = __halves2half2(__float2half(v0), __float2half(v1));
        rec.h2[1] = __halves2half2(__float2half(v2), __float2half(v3));
        *reinterpret_cast<unsigned long long*>(lds + (size_t)tid * ROW_B) = rec.u;
    }
    __syncthreads();

    int   idxA[FANIN], idxB[FANIN];
    float wA[FANIN],   wB[FANIN];

    // preload layer 0, sweep 0
    load_edges(src, wsrc, tid, idxA, wA);

    for (int l = 0; l < NLAYERS - 1; ++l) {
        const float* bl = biases + (size_t)l * NPL;
        const int wbase = N_IN + l * NPL;

        // issue sweep-1 edge loads before sweep-0 compute
        load_edges(src, wsrc, l * NPL + 1024 + tid, idxB, wB);

        node_tanh(idxA, wA, bl[tid], wbase + tid, lds);

        // issue NEXT-layer sweep-0 loads (or final-layer loads) before the
        // barrier: latency hides under sweep-1 compute + barrier drain
        if (l < NLAYERS - 2) {
            load_edges(src, wsrc, (l + 1) * NPL + tid, idxA, wA);
        } else if (tid < N_OUT) {
            load_edges(src, wsrc, 4 * NPL + (NPL - N_OUT) + tid, idxA, wA);
        }

        node_tanh(idxB, wB, bl[1024 + tid], wbase + 1024 + tid, lds);
        __syncthreads();
    }

    // ---- layer 4: last N_OUT nodes only; f32 accum; sigmoid; f32 out ----
    if (tid < N_OUT) {
        const float bv = biases[(size_t)4 * NPL + (NPL - N_OUT) + tid];
        float a0 = bv, a1 = bv, a2 = bv, a3 = bv;
#pragma unroll
        for (int f = 0; f < FANIN; ++f) {
            H4 v;
            v.u = *reinterpret_cast<const unsigned long long*>(
                lds + ((unsigned)idxA[f] << 3));
            const float wf = wA[f];
            a0 = fmaf(__half2float(v.h2[0].x), wf, a0);
            a1 = fmaf(__half2float(v.h2[0].y), wf, a1);
            a2 = fmaf(__half2float(v.h2[1].x), wf, a2);
            a3 = fmaf(__half2float(v.h2[1].y), wf, a3);
        }
        a0 = fast_sigmoid(a0); a1 = fast_sigmoid(a1);
        a2 = fast_sigmoid(a2); a3 = fast_sigmoid(a3);
        const int j = tid;                               // output column
        out[(size_t)(c0 + 0) * N_OUT + j] = a0;
        out[(size_t)(c0 + 1) * N_OUT + j] = a1;
        out[(size_t)(c0 + 2) * N_OUT + j] = a2;
        out[(size_t)(c0 + 3) * N_OUT + j] = a3;
    }
}

// ---------------------------------------------------------------------------
// Launch: ONE kernel. 256 blocks x 1024 threads, 73728 B dynamic LDS.
// d_ws unused.
// ---------------------------------------------------------------------------
extern "C" void kernel_launch(void* const* d_in, const int* in_sizes, int n_in,
                              void* d_out, int out_size, void* d_ws, size_t ws_size,
                              hipStream_t stream)
{
    const float* inputs   = (const float*)d_in[0];
    const int*   edge_src = (const int*)  d_in[1];
    const float* edge_w   = (const float*)d_in[2];
    const float* biases   = (const float*)d_in[3];
    float* out = (float*)d_out;

    fused_net_kernel<<<NBLK, 1024, LDS_BYTES, stream>>>(
        inputs, edge_src, edge_w, biases, out);
}